// Round 2
// baseline (438.411 us; speedup 1.0000x reference)
//
#include <hip/hip_runtime.h>

// LSGA fused kernel, round 2: fp32 inputs/outputs (reference declares float32;
// round-1 NaN diagnosed as fp32-read-as-bf16). Fused weights converted to bf16
// only for LDS staging (error ~0.4% rel << 2% threshold).
//
// Algebra (exact given sum(attn)=1):
//   qk   = A·x_n + bA,            A = Wk^T Wq, bA = Wk^T bq          [128]
//   s[k] = (qk·x_nb[k] + h[k]·g + qk·b2 + x_n·u + bq·bk)/sqrt(C)
//          g = W2·qk [32], u = Wq^T bk, h[k] = relu(E[k]·W1 + b1)
//   attn = softmax_k(s)
//   w    = sum_k attn[k]*x_nb[k] + W2^T·(sum_k attn[k]*h[k]) + b2    [128]
//   out  = Wov·w + bov,           Wov = Wo·Wv, bov = Wo·bv + bo

using u16 = unsigned short;
using u32 = unsigned int;

#define NPER 16   // n's per block in main kernel; grid = 2*8192/NPER = 1024

__device__ __forceinline__ float bl(u32 u) { return __uint_as_float(u << 16); }
__device__ __forceinline__ float bh(u32 u) { return __uint_as_float(u & 0xffff0000u); }
__device__ __forceinline__ float b2f(u16 u) { return __uint_as_float(((u32)u) << 16); }
__device__ __forceinline__ u16 f2b(float f) {
    u32 u = __float_as_uint(f);
    u32 r = u + 0x7fffu + ((u >> 16) & 1u);   // RNE
    return (u16)(r >> 16);
}
// dot of 8 bf16 (one uint4) with 8 fp32 (two float4, 16B-aligned)
__device__ __forceinline__ float dot8(uint4 wv, const float* xp) {
    float4 a = *(const float4*)xp;
    float4 b = *(const float4*)(xp + 4);
    return bl(wv.x)*a.x + bh(wv.x)*a.y + bl(wv.y)*a.z + bh(wv.y)*a.w
         + bl(wv.z)*b.x + bh(wv.z)*b.y + bl(wv.w)*b.z + bh(wv.w)*b.w;
}

// ---------------------------------------------------------------------------
// Kernel 1: fuse weights (fp32 in, bf16 fused weights + fp32 biases out).
// Grid 128 x 128. Block r computes row r of A and Wov; r<32 also W1t/W2c;
// r==0 does bias vectors.
__global__ void k_prep(const float* __restrict__ Wq, const float* __restrict__ bq,
                       const float* __restrict__ Wk, const float* __restrict__ bk,
                       const float* __restrict__ Wv, const float* __restrict__ bv,
                       const float* __restrict__ Wo, const float* __restrict__ bo,
                       const float* __restrict__ W1, const float* __restrict__ W2,
                       u16* __restrict__ A, u16* __restrict__ Wov,
                       u16* __restrict__ W1t, u16* __restrict__ W2c,
                       float* __restrict__ bA, float* __restrict__ u,
                       float* __restrict__ bov, float* __restrict__ d0)
{
    const int r = blockIdx.x, i = threadIdx.x;
    float accA = 0.f, accV = 0.f;
    for (int o = 0; o < 128; ++o)
        accA += Wk[o*128 + r] * Wq[o*128 + i];   // A[r][i] = sum_o Wk[o][r] Wq[o][i]
    A[r*128 + i] = f2b(accA);
    for (int p = 0; p < 128; ++p)
        accV += Wo[r*128 + p] * Wv[p*128 + i];   // Wov[r][i] = sum_p Wo[r][p] Wv[p][i]
    Wov[r*128 + i] = f2b(accV);
    if (r < 32) {
        W1t[r*128 + i] = f2b(W1[i*32 + r]);      // W1t[m][i] = W1[i][m]
        W2c[r*128 + i] = f2b(W2[r*128 + i]);
    }
    if (r == 0) {
        float a1 = 0.f, a2 = 0.f, a3 = 0.f;
        for (int o = 0; o < 128; ++o) a1 += Wk[o*128 + i] * bq[o];
        bA[i] = a1;
        for (int o = 0; o < 128; ++o) a2 += Wq[o*128 + i] * bk[o];
        u[i] = a2;
        for (int p = 0; p < 128; ++p) a3 += Wo[i*128 + p] * bv[p];
        bov[i] = a3 + bo[i];
        if (i == 0) {
            float s = 0.f;
            for (int o = 0; o < 128; ++o) s += bq[o] * bk[o];
            *d0 = s;
        }
    }
}

// ---------------------------------------------------------------------------
// Kernel 2: transpose x[b][c][n] (fp32) -> xT[b][n][c] (bf16). Grid 2048 x 256.
__global__ void k_tr(const float* __restrict__ x, u16* __restrict__ xT)
{
    __shared__ u16 tile[32][33];
    const int blk = blockIdx.x;
    const int b  = blk >> 10;          // 2
    const int ct = (blk >> 8) & 3;     // C/32 = 4
    const int nt = blk & 255;          // N/32 = 256
    const int tx = threadIdx.x & 31, ty = threadIdx.x >> 5;  // 32 x 8
    const size_t xb = (size_t)b * 128 * 8192;
    #pragma unroll
    for (int j = 0; j < 4; ++j) {
        int c = ct*32 + ty + j*8;
        tile[ty + j*8][tx] = f2b(x[xb + (size_t)c * 8192 + (size_t)(nt*32 + tx)]);
    }
    __syncthreads();
    #pragma unroll
    for (int j = 0; j < 4; ++j) {
        int n = nt*32 + ty + j*8;
        xT[xb + (size_t)n * 128 + (size_t)(ct*32 + tx)] = tile[tx][ty + j*8];
    }
}

// ---------------------------------------------------------------------------
// Kernel 3: fused main. Grid 1024 x 512. ~110 KB LDS -> 1 block/CU, 8 waves.
__global__ void __launch_bounds__(512)
k_main(const u16* __restrict__ xT, const float* __restrict__ coords,
       const int* __restrict__ idx,
       const float* __restrict__ Bg, const u16* __restrict__ W1tg,
       const u16* __restrict__ W2g, const float* __restrict__ b1g, const float* __restrict__ b2g,
       const u16* __restrict__ Ag, const u16* __restrict__ Wovg,
       const float* __restrict__ bAg, const float* __restrict__ ug,
       const float* __restrict__ bovg, const float* __restrict__ d0g,
       float* __restrict__ out)
{
    // weights (rows padded to 136 bf16 = 272B = 17*16B -> b128 reads spread all 32 banks)
    __shared__ __align__(16) u16 sA[128][136];
    __shared__ __align__(16) u16 sWov[128][136];
    __shared__ __align__(16) u16 sW1t[32][136];
    __shared__ __align__(16) u16 sW2[32][136];
    __shared__ __align__(16) float sBg[4][64];
    __shared__ float sb1[32], sb2[128], sbA[128], su[128], sbov[128];
    // per-n working set
    __shared__ __align__(16) float s_xn[128];
    __shared__ __align__(16) u16 s_xnb[16][136];
    __shared__ float s_delta[16][4];
    __shared__ __align__(16) float sE[16][132];   // row = 528B = 33*16B
    __shared__ float sh[16][33];
    __shared__ __align__(16) float s_qk[128];
    __shared__ float s_g[32];
    __shared__ float s_sp[16][17];
    __shared__ float s_red[32];
    __shared__ float s_attn[16];
    __shared__ float s_hbar[32];
    __shared__ float s_part[4][128];
    __shared__ __align__(16) float s_w[128];
    __shared__ int s_idx[16];

    const int tid = threadIdx.x;
    const float inv_sqrtC = 0.08838834764831845f;  // 1/sqrt(128)

    // ---- stage weights once per block ----
    for (int e = tid; e < 128*16; e += 512) {
        int r = e >> 4, c = e & 15;
        *(uint4*)&sA[r][c*8]   = ((const uint4*)Ag)[e];
        *(uint4*)&sWov[r][c*8] = ((const uint4*)Wovg)[e];
    }
    for (int e = tid; e < 32*16; e += 512) {
        int r = e >> 4, c = e & 15;
        *(uint4*)&sW1t[r][c*8] = ((const uint4*)W1tg)[e];
        *(uint4*)&sW2[r][c*8]  = ((const uint4*)W2g)[e];
    }
    if (tid < 128) {
        sbA[tid] = bAg[tid]; su[tid] = ug[tid]; sbov[tid] = bovg[tid];
        sb2[tid] = b2g[tid];
    } else if (tid < 160) {
        sb1[tid-128] = b1g[tid-128];
    } else if (tid >= 256) {
        int q = tid - 256;                 // 256 threads for 4*64 entries
        sBg[q >> 6][q & 63] = Bg[q];
    }
    const float c_d0 = *d0g;
    __syncthreads();

    for (int it = 0; it < NPER; ++it) {
        const int g = blockIdx.x * NPER + it;       // g = b*N + n
        const int b = g >> 13;
        const int n = g & 8191;
        const size_t baseBN = ((size_t)b << 13);

        // (a) load idx + center feature column
        if (tid < 16) s_idx[tid] = idx[(size_t)g * 16 + tid];
        if (tid >= 64 && tid < 192) {
            int c = tid - 64;
            s_xn[c] = b2f(xT[((size_t)g << 7) + c]);
        }
        __syncthreads();

        // (b) gather neighbors + deltas; qk split-4 partials
        const int kk = tid >> 5, c4 = (tid & 31) << 2;
        const ushort4 nbv = *(const ushort4*)&xT[(((size_t)(baseBN + s_idx[kk])) << 7) + c4];
        float dreg = 0.f;
        const int kd = tid >> 2, dd = tid & 3;
        if (tid < 64) {
            int j = s_idx[kd];
            dreg = coords[(size_t)(baseBN + j)*4 + dd] - coords[(size_t)g*4 + dd];
        }
        {
            const int cq = tid & 127, iq = tid >> 7;
            float acc = 0.f;
            #pragma unroll
            for (int jj = 0; jj < 4; ++jj) {
                int i0 = iq*32 + jj*8;
                acc += dot8(*(const uint4*)&sA[cq][i0], &s_xn[i0]);
            }
            s_part[iq][cq] = acc;
        }
        *(ushort4*)&s_xnb[kk][c4] = nbv;
        if (tid < 64) s_delta[kd][dd] = dreg;
        __syncthreads();

        // (c) qk reduce (waves 0-1) || fourier E (wave 2-3)
        if (tid < 128) {
            s_qk[tid] = s_part[0][tid] + s_part[1][tid] + s_part[2][tid]
                      + s_part[3][tid] + sbA[tid];
        } else if (tid < 256) {
            int t = tid - 128;
            int k = t >> 3, f0 = (t & 7) * 8;
            float e0 = s_delta[k][0], e1 = s_delta[k][1], e2 = s_delta[k][2], e3 = s_delta[k][3];
            #pragma unroll
            for (int f = f0; f < f0 + 8; ++f) {
                float p = e0*sBg[0][f] + e1*sBg[1][f] + e2*sBg[2][f] + e3*sBg[3][f];
                float r = p - floorf(p);            // v_sin/v_cos take revolutions
                sE[k][f]      = __builtin_amdgcn_sinf(r);
                sE[k][64 + f] = __builtin_amdgcn_cosf(r);
            }
        }
        __syncthreads();

        // (d) MLP layer-1: all 512 threads, one (k,m) output each
        {
            const int k = tid >> 5, m = tid & 31;
            float acc = sb1[m];
            #pragma unroll
            for (int i8 = 0; i8 < 16; ++i8)
                acc += dot8(*(const uint4*)&sW1t[m][i8*8], &sE[k][i8*8]);
            sh[k][m] = fmaxf(acc, 0.f);
        }
        // (e) same phase (independent of (d) outputs): g, e0t0 partials, qk·x_nb partials
        if (tid < 32) {
            const int m = tid;
            float acc = 0.f;
            #pragma unroll
            for (int c8 = 0; c8 < 16; ++c8)
                acc += dot8(*(const uint4*)&sW2[m][c8*8], &s_qk[c8*8]);
            s_g[m] = acc;
        } else if (tid >= 64 && tid < 96) {
            const int j = tid - 64;
            float acc = 0.f;
            #pragma unroll
            for (int c = j*4; c < j*4 + 4; ++c)
                acc += s_qk[c]*sb2[c] + s_xn[c]*su[c];
            s_red[j] = acc;
        } else if (tid >= 128 && tid < 384) {
            const int t = tid - 128;
            const int k = t >> 4, j = t & 15;
            s_sp[k][j] = dot8(*(const uint4*)&s_xnb[k][j*8], &s_qk[j*8]);
        }
        __syncthreads();

        // (f) scores + softmax over K=16 (lanes 0-15 of wave 0)
        if (tid < 16) {
            const int k = tid;
            float acc = 0.f;
            #pragma unroll
            for (int j = 0; j < 16; ++j) acc += s_sp[k][j];
            #pragma unroll
            for (int m = 0; m < 32; ++m) acc += sh[k][m] * s_g[m];
            float e0t0 = c_d0;
            #pragma unroll
            for (int j = 0; j < 32; ++j) e0t0 += s_red[j];
            float s = (acc + e0t0) * inv_sqrtC;
            float mx = s;
            mx = fmaxf(mx, __shfl_xor(mx, 1, 16));
            mx = fmaxf(mx, __shfl_xor(mx, 2, 16));
            mx = fmaxf(mx, __shfl_xor(mx, 4, 16));
            mx = fmaxf(mx, __shfl_xor(mx, 8, 16));
            float ex = __expf(s - mx);
            float sm = ex;
            sm += __shfl_xor(sm, 1, 16);
            sm += __shfl_xor(sm, 2, 16);
            sm += __shfl_xor(sm, 4, 16);
            sm += __shfl_xor(sm, 8, 16);
            s_attn[k] = ex / sm;
        }
        __syncthreads();

        // (g) xbar (into s_w) and hbar
        if (tid < 128) {
            const int c = tid;
            float acc = 0.f;
            #pragma unroll
            for (int k = 0; k < 16; ++k) acc += s_attn[k] * b2f(s_xnb[k][c]);
            s_w[c] = acc;
        } else if (tid < 160) {
            const int m = tid - 128;
            float acc = 0.f;
            #pragma unroll
            for (int k = 0; k < 16; ++k) acc += s_attn[k] * sh[k][m];
            s_hbar[m] = acc;
        }
        __syncthreads();

        // (h) w = xbar + W2^T hbar + b2
        if (tid < 128) {
            const int c = tid;
            float acc = s_w[c] + sb2[c];
            #pragma unroll
            for (int m = 0; m < 32; ++m) acc += s_hbar[m] * b2f(sW2[m][c]);
            s_w[c] = acc;
        }
        __syncthreads();

        // (i) out = Wov·w + bov, split-4 partials
        {
            const int o = tid & 127, iq = tid >> 7;
            float acc = 0.f;
            #pragma unroll
            for (int jj = 0; jj < 4; ++jj) {
                int i0 = iq*32 + jj*8;
                acc += dot8(*(const uint4*)&sWov[o][i0], &s_w[i0]);
            }
            s_part[iq][o] = acc;
        }
        __syncthreads();

        // (j) reduce + store fp32 to out[b][o][n]
        if (tid < 128) {
            const int o = tid;
            float v = s_part[0][o] + s_part[1][o] + s_part[2][o] + s_part[3][o] + sbov[o];
            out[(((size_t)b*128 + o) << 13) + n] = v;
        }
        __syncthreads();   // protect per-n LDS before next iteration
    }
}

// ---------------------------------------------------------------------------
extern "C" void kernel_launch(void* const* d_in, const int* in_sizes, int n_in,
                              void* d_out, int out_size, void* d_ws, size_t ws_size,
                              hipStream_t stream)
{
    const float* x      = (const float*)d_in[0];
    const float* coords = (const float*)d_in[1];
    const int*   idx    = (const int*)d_in[2];
    const float* Bg     = (const float*)d_in[3];
    const float* W1     = (const float*)d_in[4];
    const float* b1     = (const float*)d_in[5];
    const float* W2     = (const float*)d_in[6];
    const float* b2     = (const float*)d_in[7];
    const float* Wq     = (const float*)d_in[8];
    const float* bq     = (const float*)d_in[9];
    const float* Wk     = (const float*)d_in[10];
    const float* bk     = (const float*)d_in[11];
    const float* Wv     = (const float*)d_in[12];
    const float* bv     = (const float*)d_in[13];
    const float* Wo     = (const float*)d_in[14];
    const float* bo     = (const float*)d_in[15];
    float* out = (float*)d_out;

    char* ws = (char*)d_ws;
    u16*   A    = (u16*)(ws);             // 32768 B
    u16*   Wov  = (u16*)(ws + 32768);     // 32768 B
    u16*   W1t  = (u16*)(ws + 65536);     // 8192 B
    u16*   W2c  = (u16*)(ws + 73728);     // 8192 B
    float* bA   = (float*)(ws + 81920);   // 512 B
    float* u    = (float*)(ws + 82432);   // 512 B
    float* bov  = (float*)(ws + 82944);   // 512 B
    float* d0   = (float*)(ws + 83456);   // 16 B
    u16*   xT   = (u16*)(ws + 84992);     // 2*8192*128*2 = 4 MiB

    k_prep<<<128, 128, 0, stream>>>(Wq, bq, Wk, bk, Wv, bv, Wo, bo, W1, W2,
                                    A, Wov, W1t, W2c, bA, u, bov, d0);
    k_tr<<<2048, 256, 0, stream>>>(x, xT);
    k_main<<<1024, 512, 0, stream>>>(xT, coords, idx, Bg, W1t, W2c, b1, b2,
                                     A, Wov, bA, u, bov, d0, out);
}

// Round 3
// 148.860 us; speedup vs baseline: 2.9451x; 2.9451x over previous
//
#include <hip/hip_runtime.h>

// LSGA fused kernel, round 3: MFMA-batched. 16 n's per block processed in
// parallel; all dense matmuls (QK=A*X, G=W2*QK, H=E*W1, W2T*Hbar, OUT=Wov*W)
// on the matrix pipe via 16x16x32 bf16 MFMA. 8 barriers/block (was 160).
//
// Algebra (exact given sum(attn)=1):
//   qk   = A·x_n + bA,            A = Wk^T Wq, bA = Wk^T bq          [128]
//   s[k] = (qk·x_nb[k] + h[k]·g + qk·b2 + x_n·u + bq·bk)/sqrt(C)
//          g = W2·qk [32], u = Wq^T bk, h[k] = relu(E[k]·W1 + b1)
//   attn = softmax_k(s)
//   w    = sum_k attn[k]*x_nb[k] + W2^T·(sum_k attn[k]*h[k]) + b2    [128]
//   out  = Wov·w + bov,           Wov = Wo·Wv, bov = Wo·bv + bo
//
// MFMA lane mappings (m89/m120-verified):
//   A-frag:  A[m = lane&15][k = (lane>>4)*8 + j], j=0..7
//   B-frag:  B[k = (lane>>4)*8 + j][n = lane&15]
//   C/D:     col = lane&15, row = (lane>>4)*4 + reg

using u16 = unsigned short;
using u32 = unsigned int;

typedef short bf16x8 __attribute__((ext_vector_type(8)));
typedef float f32x4  __attribute__((ext_vector_type(4)));

__device__ __forceinline__ float bl(u32 u) { return __uint_as_float(u << 16); }
__device__ __forceinline__ float bh(u32 u) { return __uint_as_float(u & 0xffff0000u); }
__device__ __forceinline__ float b2f(u16 u) { return __uint_as_float(((u32)u) << 16); }
__device__ __forceinline__ u16 f2b(float f) {
    u32 u = __float_as_uint(f);
    u32 r = u + 0x7fffu + ((u >> 16) & 1u);   // RNE
    return (u16)(r >> 16);
}
__device__ __forceinline__ u32 pack2(float a, float b) {
    return (u32)f2b(a) | ((u32)f2b(b) << 16);
}
// dot of 8 bf16 (one uint4) with 8 fp32 (two float4, 16B-aligned)
__device__ __forceinline__ float dot8(uint4 wv, const float* xp) {
    float4 a = *(const float4*)xp;
    float4 b = *(const float4*)(xp + 4);
    return bl(wv.x)*a.x + bh(wv.x)*a.y + bl(wv.y)*a.z + bh(wv.y)*a.w
         + bl(wv.z)*b.x + bh(wv.z)*b.y + bl(wv.w)*b.z + bh(wv.w)*b.w;
}
// swizzled byte offset into 256B-row bf16 buffer (16B-granule XOR)
__device__ __forceinline__ int sw(int row, int byteoff) {
    return (row << 8) + (byteoff ^ ((row & 7) << 4));
}

// ---------------------------------------------------------------------------
// Kernel 1: fuse weights + pack MFMA fragments. Grid 128 x 128.
__global__ void k_prep(const float* __restrict__ Wq, const float* __restrict__ bq,
                       const float* __restrict__ Wk, const float* __restrict__ bk,
                       const float* __restrict__ Wv, const float* __restrict__ bv,
                       const float* __restrict__ Wo, const float* __restrict__ bo,
                       const float* __restrict__ W1, const float* __restrict__ W2,
                       u16* __restrict__ Afrag, u16* __restrict__ Wovfrag,
                       u16* __restrict__ W1frag, u16* __restrict__ W2frag,
                       u16* __restrict__ W2Tfrag,
                       float* __restrict__ bA, float* __restrict__ su,
                       float* __restrict__ bov, float* __restrict__ d0)
{
    __shared__ float sWkc[128];   // Wk[o][r] column for this block's r
    __shared__ float sWor[128];   // Wo[r][p] row
    const int r = blockIdx.x, i = threadIdx.x;
    sWkc[i] = Wk[i*128 + r];
    sWor[i] = Wo[r*128 + i];
    __syncthreads();

    float accA = 0.f, accV = 0.f;
    for (int o = 0; o < 128; ++o) accA += sWkc[o] * Wq[o*128 + i];
    for (int p = 0; p < 128; ++p) accV += sWor[p] * Wv[p*128 + i];

    // A-operand frag index for element [m][c]: mt=m>>4, lm=m&15, ks=c>>5,
    // q=(c>>3)&3, j=c&7 -> frag[((mt*4+ks)*64 + q*16+lm)*8 + j]
    {
        const int mt = r >> 4, lm = r & 15;
        const int ks = i >> 5, q = (i >> 3) & 3, j = i & 7;
        const int fi = ((mt*4 + ks)*64 + q*16 + lm)*8 + j;
        Afrag[fi]   = f2b(accA);   // A[r][i]
        Wovfrag[fi] = f2b(accV);   // Wov[r][i]
    }
    if (r < 32) {
        // W1frag: B-operand of H=E*W1. elem B[k=f][n=m]: f=i, m=r
        {
            const int nt = r >> 4, lm = r & 15;
            const int ks = i >> 5, q = (i >> 3) & 3, j = i & 7;
            W1frag[((nt*4 + ks)*64 + q*16 + lm)*8 + j] = f2b(W1[i*32 + r]);
        }
        // W2frag: A-operand of G=W2*QK. elem A[m=r][c=i]
        {
            const int mt = r >> 4, lm = r & 15;
            const int ks = i >> 5, q = (i >> 3) & 3, j = i & 7;
            W2frag[((mt*4 + ks)*64 + q*16 + lm)*8 + j] = f2b(W2[r*128 + i]);
        }
        // W2Tfrag: A-operand of W2T*Hbar. elem A[c=i][m=r] (K=32, 1 k-step)
        {
            const int mt = i >> 4, lm = i & 15;
            const int q = r >> 3, j = r & 7;
            W2Tfrag[(mt*64 + q*16 + lm)*8 + j] = f2b(W2[r*128 + i]);
        }
    }
    if (r == 0) {
        float a1 = 0.f, a2 = 0.f, a3 = 0.f;
        for (int o = 0; o < 128; ++o) a1 += Wk[o*128 + i] * bq[o];
        bA[i] = a1;
        for (int o = 0; o < 128; ++o) a2 += Wq[o*128 + i] * bk[o];
        su[i] = a2;
        for (int p = 0; p < 128; ++p) a3 += Wo[i*128 + p] * bv[p];
        bov[i] = a3 + bo[i];
        if (i == 0) {
            float s = 0.f;
            for (int o = 0; o < 128; ++o) s += bq[o] * bk[o];
            *d0 = s;
        }
    }
}

// ---------------------------------------------------------------------------
// Kernel 2: transpose x[b][c][n] (fp32) -> xT[b][n][c] (bf16). Grid 2048 x 256.
__global__ void k_tr(const float* __restrict__ x, u16* __restrict__ xT)
{
    __shared__ u16 tile[32][33];
    const int blk = blockIdx.x;
    const int b  = blk >> 10;
    const int ct = (blk >> 8) & 3;
    const int nt = blk & 255;
    const int tx = threadIdx.x & 31, ty = threadIdx.x >> 5;
    const size_t xb = (size_t)b * 128 * 8192;
    #pragma unroll
    for (int j = 0; j < 4; ++j) {
        int c = ct*32 + ty + j*8;
        tile[ty + j*8][tx] = f2b(x[xb + (size_t)c * 8192 + (size_t)(nt*32 + tx)]);
    }
    __syncthreads();
    #pragma unroll
    for (int j = 0; j < 4; ++j) {
        int n = nt*32 + ty + j*8;
        xT[xb + (size_t)n * 128 + (size_t)(ct*32 + tx)] = tile[tx][ty + j*8];
    }
}

// ---------------------------------------------------------------------------
// Kernel 3: fused main, MFMA-batched. Grid 1024 x 512; 16 n per block.
__global__ void __launch_bounds__(512)
k_main(const u16* __restrict__ xT, const float* __restrict__ coords,
       const int* __restrict__ idx, const float* __restrict__ Bg,
       const float* __restrict__ b1g, const float* __restrict__ b2g,
       const u16* __restrict__ Afrag, const u16* __restrict__ Wovfrag,
       const u16* __restrict__ W1frag, const u16* __restrict__ W2frag,
       const u16* __restrict__ W2Tfrag,
       const float* __restrict__ bAg, const float* __restrict__ sug,
       const float* __restrict__ bovg, const float* __restrict__ d0g,
       float* __restrict__ out)
{
    __shared__ __align__(16) u16   buf[256*128];     // 64 KB: E then x_nb (swizzled)
    __shared__ __align__(16) u16   sH[256][40];      // 20 KB: H bf16
    __shared__ __align__(16) float s_qk[16][132];    // qk[n][c] f32
    __shared__ u16   s_qkb[128][18];                 // qk bf16 [c][n]
    __shared__ float s_wt[128][17];                  // W f32 [c][n]
    __shared__ u16   s_wtb[128][18];                 // W bf16 [c][n]
    __shared__ __align__(16) float s_del[256][4];    // deltas per (n,k)
    __shared__ __align__(16) float s_g[16][36];      // g[n][m]
    __shared__ float s_e0[16];
    __shared__ float s_attn[16][17];
    __shared__ u16   sHbar[32][18];                  // hbar bf16 [m][n]
    __shared__ __align__(16) float s_b2[128], s_su[128];
    __shared__ float s_bA[128], s_bov[128], s_b1[32];
    __shared__ __align__(16) float sBgT[64][4];

    const int tid = threadIdx.x;
    const int w = tid >> 6, l = tid & 63, lm = l & 15, lq = l >> 4;
    const int g0 = blockIdx.x * 16;          // base of 16 consecutive (b,n)
    const int bsel = g0 >> 13;
    const int n0 = g0 & 8191;
    const size_t bbase = ((size_t)bsel) << 13;
    const float inv_sqrtC = 0.08838834764831845f;
    char* bb = (char*)buf;

    // ---- preamble: stage biases / Bg ----
    if (tid < 128) {
        s_bA[tid] = bAg[tid]; s_su[tid] = sug[tid];
        s_bov[tid] = bovg[tid]; s_b2[tid] = b2g[tid];
    } else if (tid < 160) {
        s_b1[tid-128] = b1g[tid-128];
    } else if (tid >= 256) {
        int q = tid - 256;                   // 256 entries: [f][d]
        sBgT[q >> 2][q & 3] = Bg[(q & 3)*64 + (q >> 2)];
    }
    const float c_d0 = *d0g;

    // ---- P1: deltas gather + QK = A*X (MFMA) ----
    if (tid < 256) {
        int j = idx[(size_t)g0*16 + tid];
        float4 cj = *(const float4*)&coords[(size_t)(bbase + j)*4];
        float4 cn = *(const float4*)&coords[(size_t)(g0 + (tid >> 4))*4];
        float4 dv = make_float4(cj.x-cn.x, cj.y-cn.y, cj.z-cn.z, cj.w-cn.w);
        *(float4*)s_del[tid] = dv;
    }
    f32x4 accq = {0.f, 0.f, 0.f, 0.f};
    {
        const bf16x8* Af = (const bf16x8*)Afrag;
        #pragma unroll
        for (int ks = 0; ks < 4; ++ks) {
            bf16x8 a = Af[(w*4 + ks)*64 + l];
            bf16x8 bfr = *(const bf16x8*)&xT[(((size_t)(g0 + lm)) << 7) + ks*32 + lq*8];
            accq = __builtin_amdgcn_mfma_f32_16x16x32_bf16(a, bfr, accq, 0, 0, 0);
        }
    }
    __syncthreads();
    // write qk (f32 [n][c] and bf16 [c][n])
    #pragma unroll
    for (int r = 0; r < 4; ++r) {
        int c = w*16 + lq*4 + r;
        float v = accq[r] + s_bA[c];
        s_qk[lm][c] = v;
        s_qkb[c][lm] = f2b(v);
    }

    // ---- P2: Fourier E -> buf (bf16, swizzled) ----
    {
        int row = tid >> 1, f0 = (tid & 1) * 32;
        float4 d = *(const float4*)s_del[row];
        #pragma unroll
        for (int fp = 0; fp < 16; ++fp) {
            int f = f0 + fp*2;
            float4 ga = *(const float4*)sBgT[f];
            float4 gb = *(const float4*)sBgT[f+1];
            float p0 = d.x*ga.x + d.y*ga.y + d.z*ga.z + d.w*ga.w;
            float p1 = d.x*gb.x + d.y*gb.y + d.z*gb.z + d.w*gb.w;
            p0 -= floorf(p0); p1 -= floorf(p1);
            float s0 = __builtin_amdgcn_sinf(p0), s1 = __builtin_amdgcn_sinf(p1);
            float c0 = __builtin_amdgcn_cosf(p0), c1 = __builtin_amdgcn_cosf(p1);
            *(u32*)(bb + sw(row, 2*f))       = pack2(s0, s1);   // sin at f..f+1
            *(u32*)(bb + sw(row, 128 + 2*f)) = pack2(c0, c1);   // cos at 64+f
        }
    }
    __syncthreads();

    // ---- P3: H = relu(E*W1 + b1) [all waves] ; G = W2*QK [waves 0-1] ; e0t0 ----
    {
        const bf16x8* W1f = (const bf16x8*)W1frag;
        bf16x8 w1f[2][4];
        #pragma unroll
        for (int nt = 0; nt < 2; ++nt)
            #pragma unroll
            for (int ks = 0; ks < 4; ++ks) w1f[nt][ks] = W1f[(nt*4 + ks)*64 + l];
        f32x4 acch[2][2];
        #pragma unroll
        for (int a0 = 0; a0 < 2; ++a0)
            #pragma unroll
            for (int a1 = 0; a1 < 2; ++a1) acch[a0][a1] = (f32x4){0.f,0.f,0.f,0.f};
        #pragma unroll
        for (int mi = 0; mi < 2; ++mi) {
            int mt = w*2 + mi;
            #pragma unroll
            for (int ks = 0; ks < 4; ++ks) {
                bf16x8 a = *(const bf16x8*)(bb + sw(mt*16 + lm, ks*64 + lq*16));
                acch[mi][0] = __builtin_amdgcn_mfma_f32_16x16x32_bf16(a, w1f[0][ks], acch[mi][0], 0,0,0);
                acch[mi][1] = __builtin_amdgcn_mfma_f32_16x16x32_bf16(a, w1f[1][ks], acch[mi][1], 0,0,0);
            }
        }
        #pragma unroll
        for (int nt = 0; nt < 2; ++nt) {
            float b1v = s_b1[nt*16 + lm];
            #pragma unroll
            for (int mi = 0; mi < 2; ++mi)
                #pragma unroll
                for (int r = 0; r < 4; ++r) {
                    int row = (w*2 + mi)*16 + lq*4 + r;
                    sH[row][nt*16 + lm] = f2b(fmaxf(acch[mi][nt][r] + b1v, 0.f));
                }
        }
    }
    if (w < 2) {
        const bf16x8* W2f = (const bf16x8*)W2frag;
        f32x4 accg = {0.f,0.f,0.f,0.f};
        #pragma unroll
        for (int ks = 0; ks < 4; ++ks) {
            bf16x8 a = W2f[(w*4 + ks)*64 + l];
            bf16x8 bv;
            #pragma unroll
            for (int j = 0; j < 8; ++j) bv[j] = (short)s_qkb[ks*32 + lq*8 + j][lm];
            accg = __builtin_amdgcn_mfma_f32_16x16x32_bf16(a, bv, accg, 0, 0, 0);
        }
        #pragma unroll
        for (int r = 0; r < 4; ++r) s_g[lm][w*16 + lq*4 + r] = accg[r];
    }
    {   // e0t0[n] = qk·b2 + x_n·u + d0, reduced over 32-thread groups
        int n = tid >> 5, sl = tid & 31, c0 = sl*4;
        float4 qv  = *(const float4*)&s_qk[n][c0];
        float4 b2v = *(const float4*)&s_b2[c0];
        float4 suv = *(const float4*)&s_su[c0];
        ushort4 xv = *(const ushort4*)&xT[(((size_t)(g0 + n)) << 7) + c0];
        float part = qv.x*b2v.x + qv.y*b2v.y + qv.z*b2v.z + qv.w*b2v.w
                   + b2f(xv.x)*suv.x + b2f(xv.y)*suv.y + b2f(xv.z)*suv.z + b2f(xv.w)*suv.w;
        part += __shfl_xor(part, 1, 32);
        part += __shfl_xor(part, 2, 32);
        part += __shfl_xor(part, 4, 32);
        part += __shfl_xor(part, 8, 32);
        part += __shfl_xor(part, 16, 32);
        if (sl == 0) s_e0[n] = part + c_d0;
    }
    __syncthreads();

    // ---- P4: x_nb gather -> buf (overwrite E) ----
    #pragma unroll
    for (int i = 0; i < 8; ++i) {
        int row = w*32 + i*4 + lq;
        int j = idx[(size_t)g0*16 + row];
        uint4 v = *(const uint4*)&xT[(((size_t)(bbase + j)) << 7) + lm*8];
        *(uint4*)(bb + sw(row, lm*16)) = v;
    }
    __syncthreads();

    // ---- P5: scores + softmax (threads 0..255, one per (n,k)) ----
    if (tid < 256) {
        int n = tid >> 4, row = tid;
        float acc = 0.f;
        #pragma unroll
        for (int j = 0; j < 16; ++j)
            acc += dot8(*(const uint4*)(bb + sw(row, j*16)), &s_qk[n][j*8]);
        #pragma unroll
        for (int jm = 0; jm < 4; ++jm)
            acc += dot8(*(const uint4*)&sH[row][jm*8], &s_g[n][jm*8]);
        float s = (acc + s_e0[n]) * inv_sqrtC;
        float mx = s;
        mx = fmaxf(mx, __shfl_xor(mx, 1, 16));
        mx = fmaxf(mx, __shfl_xor(mx, 2, 16));
        mx = fmaxf(mx, __shfl_xor(mx, 4, 16));
        mx = fmaxf(mx, __shfl_xor(mx, 8, 16));
        float ex = __expf(s - mx);
        float sm = ex;
        sm += __shfl_xor(sm, 1, 16);
        sm += __shfl_xor(sm, 2, 16);
        sm += __shfl_xor(sm, 4, 16);
        sm += __shfl_xor(sm, 8, 16);
        s_attn[n][tid & 15] = ex / sm;
    }
    __syncthreads();

    // ---- P6: xbar (+b2) -> s_wt ; hbar -> sHbar ----
    {
        int n = tid >> 5, cs = tid & 31, c0 = cs*4;
        float4 facc = *(const float4*)&s_b2[c0];
        #pragma unroll
        for (int k = 0; k < 16; ++k) {
            float a = s_attn[n][k];
            uint2 v = *(const uint2*)(bb + sw(n*16 + k, c0*2));
            facc.x += a*bl(v.x); facc.y += a*bh(v.x);
            facc.z += a*bl(v.y); facc.w += a*bh(v.y);
        }
        s_wt[c0  ][n] = facc.x; s_wt[c0+1][n] = facc.y;
        s_wt[c0+2][n] = facc.z; s_wt[c0+3][n] = facc.w;
        int m = tid & 31;
        float hacc = 0.f;
        #pragma unroll
        for (int k = 0; k < 16; ++k) hacc += s_attn[n][k] * b2f(sH[n*16 + k][m]);
        sHbar[m][n] = f2b(hacc);
    }
    __syncthreads();

    // ---- P7: W += W2T*Hbar (MFMA, K=32) ; convert to bf16 ----
    {
        const bf16x8* W2Tf = (const bf16x8*)W2Tfrag;
        bf16x8 a = W2Tf[w*64 + l];
        bf16x8 bv;
        #pragma unroll
        for (int j = 0; j < 8; ++j) bv[j] = (short)sHbar[lq*8 + j][lm];
        f32x4 accw = {0.f,0.f,0.f,0.f};
        accw = __builtin_amdgcn_mfma_f32_16x16x32_bf16(a, bv, accw, 0, 0, 0);
        #pragma unroll
        for (int r = 0; r < 4; ++r) {
            int c = w*16 + lq*4 + r;
            s_wtb[c][lm] = f2b(s_wt[c][lm] + accw[r]);
        }
    }
    __syncthreads();

    // ---- P8: OUT = Wov*W + bov (MFMA) -> global ----
    {
        const bf16x8* Wvf = (const bf16x8*)Wovfrag;
        f32x4 acco = {0.f,0.f,0.f,0.f};
        #pragma unroll
        for (int ks = 0; ks < 4; ++ks) {
            bf16x8 a = Wvf[(w*4 + ks)*64 + l];
            bf16x8 bv;
            #pragma unroll
            for (int j = 0; j < 8; ++j) bv[j] = (short)s_wtb[ks*32 + lq*8 + j][lm];
            acco = __builtin_amdgcn_mfma_f32_16x16x32_bf16(a, bv, acco, 0, 0, 0);
        }
        #pragma unroll
        for (int r = 0; r < 4; ++r) {
            int o = w*16 + lq*4 + r;
            out[(((size_t)(bsel*128 + o)) << 13) + n0 + lm] = acco[r] + s_bov[o];
        }
    }
}

// ---------------------------------------------------------------------------
extern "C" void kernel_launch(void* const* d_in, const int* in_sizes, int n_in,
                              void* d_out, int out_size, void* d_ws, size_t ws_size,
                              hipStream_t stream)
{
    const float* x      = (const float*)d_in[0];
    const float* coords = (const float*)d_in[1];
    const int*   idx    = (const int*)d_in[2];
    const float* Bg     = (const float*)d_in[3];
    const float* W1     = (const float*)d_in[4];
    const float* b1     = (const float*)d_in[5];
    const float* W2     = (const float*)d_in[6];
    const float* b2     = (const float*)d_in[7];
    const float* Wq     = (const float*)d_in[8];
    const float* bq     = (const float*)d_in[9];
    const float* Wk     = (const float*)d_in[10];
    const float* bk     = (const float*)d_in[11];
    const float* Wv     = (const float*)d_in[12];
    const float* bv     = (const float*)d_in[13];
    const float* Wo     = (const float*)d_in[14];
    const float* bo     = (const float*)d_in[15];
    float* out = (float*)d_out;

    char* ws = (char*)d_ws;
    u16*   Afrag   = (u16*)(ws);              // 32768 B
    u16*   Wovfrag = (u16*)(ws + 32768);      // 32768 B
    u16*   W1frag  = (u16*)(ws + 65536);      // 8192 B
    u16*   W2frag  = (u16*)(ws + 73728);      // 8192 B
    u16*   W2Tfrag = (u16*)(ws + 81920);      // 8192 B
    float* bA      = (float*)(ws + 90112);    // 512 B
    float* su      = (float*)(ws + 90624);    // 512 B
    float* bov     = (float*)(ws + 91136);    // 512 B
    float* d0      = (float*)(ws + 91648);    // 16 B
    u16*   xT      = (u16*)(ws + 94208);      // 4 MiB

    k_prep<<<128, 128, 0, stream>>>(Wq, bq, Wk, bk, Wv, bv, Wo, bo, W1, W2,
                                    Afrag, Wovfrag, W1frag, W2frag, W2Tfrag,
                                    bA, su, bov, d0);
    k_tr<<<2048, 256, 0, stream>>>(x, xT);
    k_main<<<1024, 512, 0, stream>>>(xT, coords, idx, Bg, b1, b2,
                                     Afrag, Wovfrag, W1frag, W2frag, W2Tfrag,
                                     bA, su, bov, d0, out);
}

// Round 4
// 137.143 us; speedup vs baseline: 3.1967x; 1.0854x over previous
//
#include <hip/hip_runtime.h>

// LSGA fused kernel, round 4.
//  - k_prep: split-K parallel rewrite (was 2-wave serial loops).
//  - k_main: E computed in registers (A-frag layout, no LDS phase);
//    scores via concatenated MFMA [Xnb|H]·[qk;g]; all MFMA B-operands fed by
//    ds_read_b128 from [n][c]-layout LDS rows.
//
// Algebra (exact given sum(attn)=1):
//   qk   = A·x_n + bA,            A = Wk^T Wq, bA = Wk^T bq          [128]
//   s[k] = (qk·x_nb[k] + h[k]·g + qk·b2 + x_n·u + bq·bk)/sqrt(C)
//          g = W2·qk [32], u = Wq^T bk, h[k] = relu(E[k]·W1 + b1)
//   attn = softmax_k(s)
//   w    = sum_k attn[k]*x_nb[k] + W2^T·(sum_k attn[k]*h[k]) + b2    [128]
//   out  = Wov·w + bov,           Wov = Wo·Wv, bov = Wo·bv + bo
//
// MFMA 16x16x32 lane mappings (m89/m120-verified, reused from passing round 3):
//   A-frag:  A[m = lane&15][k = (lane>>4)*8 + j]
//   B-frag:  B[k = (lane>>4)*8 + j][n = lane&15]
//   C/D:     col = lane&15, row = (lane>>4)*4 + reg

using u16 = unsigned short;
using u32 = unsigned int;
using u64 = unsigned long long;

typedef short bf16x8 __attribute__((ext_vector_type(8)));
typedef float f32x4  __attribute__((ext_vector_type(4)));

__device__ __forceinline__ float bl(u32 u) { return __uint_as_float(u << 16); }
__device__ __forceinline__ float bh(u32 u) { return __uint_as_float(u & 0xffff0000u); }
__device__ __forceinline__ float b2f(u16 u) { return __uint_as_float(((u32)u) << 16); }
__device__ __forceinline__ u16 f2b(float f) {
    u32 u = __float_as_uint(f);
    u32 r = u + 0x7fffu + ((u >> 16) & 1u);   // RNE
    return (u16)(r >> 16);
}
__device__ __forceinline__ float dot8(uint4 wv, const float* xp) {
    float4 a = *(const float4*)xp;
    float4 b = *(const float4*)(xp + 4);
    return bl(wv.x)*a.x + bh(wv.x)*a.y + bl(wv.y)*a.z + bh(wv.y)*a.w
         + bl(wv.z)*b.x + bh(wv.z)*b.y + bl(wv.w)*b.z + bh(wv.w)*b.w;
}
__device__ __forceinline__ u64 pack4(float a, float b, float c, float d) {
    return (u64)f2b(a) | ((u64)f2b(b) << 16) | ((u64)f2b(c) << 32) | ((u64)f2b(d) << 48);
}

// A-operand frag flat index for element [m][c] of a 128-col operand
__device__ __forceinline__ int fidxA(int m, int c) {
    return (((m >> 4)*4 + (c >> 5))*64 + ((c >> 3) & 3)*16 + (m & 15))*8 + (c & 7);
}

// ---------------------------------------------------------------------------
// Kernel 1: fuse weights + pack MFMA fragments. Grid 130 x 512.
__global__ void __launch_bounds__(512)
k_prep(const float* __restrict__ Wq, const float* __restrict__ bq,
       const float* __restrict__ Wk, const float* __restrict__ bk,
       const float* __restrict__ Wv, const float* __restrict__ bv,
       const float* __restrict__ Wo, const float* __restrict__ bo,
       const float* __restrict__ W1, const float* __restrict__ W2,
       u16* __restrict__ Afrag, u16* __restrict__ Wovfrag,
       u16* __restrict__ W1frag, u16* __restrict__ W2frag,
       u16* __restrict__ W2Tfrag,
       float* __restrict__ bA, float* __restrict__ su,
       float* __restrict__ bov, float* __restrict__ d0)
{
    const int blk = blockIdx.x, tid = threadIdx.x;
    const int i = tid & 127, p = tid >> 7;          // 4-way K-split

    if (blk < 128) {
        // A row blk and Wov row blk
        __shared__ float sWk[128], sWo[128];
        __shared__ float s_pA[4][128], s_pV[4][128];
        if (tid < 128) sWk[tid] = Wk[tid*128 + blk];
        else if (tid < 256) sWo[tid-128] = Wo[blk*128 + (tid-128)];
        __syncthreads();
        float accA = 0.f, accV = 0.f;
        #pragma unroll 8
        for (int o = p*32; o < p*32 + 32; ++o) {
            accA += sWk[o] * Wq[o*128 + i];
            accV += sWo[o] * Wv[o*128 + i];
        }
        s_pA[p][i] = accA; s_pV[p][i] = accV;
        __syncthreads();
        if (tid < 128) {
            float v = s_pA[0][tid] + s_pA[1][tid] + s_pA[2][tid] + s_pA[3][tid];
            Afrag[fidxA(blk, tid)] = f2b(v);
        } else if (tid < 256) {
            int ii = tid - 128;
            float v = s_pV[0][ii] + s_pV[1][ii] + s_pV[2][ii] + s_pV[3][ii];
            Wovfrag[fidxA(blk, ii)] = f2b(v);
        }
    } else if (blk == 128) {
        // bias vectors bA, su, bov, and scalar d0
        __shared__ float s_r[3][4][128];
        float a1 = 0.f, a2 = 0.f, a3 = 0.f;
        #pragma unroll 8
        for (int o = p*32; o < p*32 + 32; ++o) {
            a1 += Wk[o*128 + i] * bq[o];
            a2 += Wq[o*128 + i] * bk[o];
            a3 += Wo[i*128 + o] * bv[o];
        }
        s_r[0][p][i] = a1; s_r[1][p][i] = a2; s_r[2][p][i] = a3;
        __syncthreads();
        if (tid < 128) {
            bA[tid] = s_r[0][0][tid] + s_r[0][1][tid] + s_r[0][2][tid] + s_r[0][3][tid];
        } else if (tid < 256) {
            int ii = tid - 128;
            su[ii] = s_r[1][0][ii] + s_r[1][1][ii] + s_r[1][2][ii] + s_r[1][3][ii];
        } else if (tid < 384) {
            int ii = tid - 256;
            bov[ii] = s_r[2][0][ii] + s_r[2][1][ii] + s_r[2][2][ii] + s_r[2][3][ii] + bo[ii];
        } else if (tid < 448) {
            int l = tid - 384;   // one wave computes d0
            float part = bq[l]*bk[l] + bq[l+64]*bk[l+64];
            part += __shfl_xor(part, 1);
            part += __shfl_xor(part, 2);
            part += __shfl_xor(part, 4);
            part += __shfl_xor(part, 8);
            part += __shfl_xor(part, 16);
            part += __shfl_xor(part, 32);
            if (l == 0) *d0 = part;
        }
    } else {
        // blk == 129: pure-permutation fragment packs for W1 / W2 / W2T
        for (int e = tid; e < 4096; e += 512) {
            int ii = e & 127, r2 = e >> 7;         // r2 in [0,32)
            // W1frag: B-operand of H=E*W1, elem B[k=ii][n=r2] = W1[ii][r2]
            {
                int nt = r2 >> 4, lmm = r2 & 15;
                int ks = ii >> 5, q = (ii >> 3) & 3, j = ii & 7;
                W1frag[((nt*4 + ks)*64 + q*16 + lmm)*8 + j] = f2b(W1[ii*32 + r2]);
            }
            // W2frag: A-operand of G=W2*QK, elem A[m=r2][c=ii]
            {
                int mt = r2 >> 4, lmm = r2 & 15;
                int ks = ii >> 5, q = (ii >> 3) & 3, j = ii & 7;
                W2frag[((mt*4 + ks)*64 + q*16 + lmm)*8 + j] = f2b(W2[r2*128 + ii]);
            }
            // W2Tfrag: A-operand of W2T*Hbar (K=32), elem A[c=ii][k=m=r2]
            {
                int mt = ii >> 4, lmm = ii & 15;
                int q = r2 >> 3, j = r2 & 7;
                W2Tfrag[(mt*64 + q*16 + lmm)*8 + j] = f2b(W2[r2*128 + ii]);
            }
        }
    }
}

// ---------------------------------------------------------------------------
// Kernel 2: transpose x[b][c][n] (fp32) -> xT[b][n][c] (bf16). Grid 2048 x 256.
__global__ void k_tr(const float* __restrict__ x, u16* __restrict__ xT)
{
    __shared__ u16 tile[32][33];
    const int blk = blockIdx.x;
    const int b  = blk >> 10;
    const int ct = (blk >> 8) & 3;
    const int nt = blk & 255;
    const int tx = threadIdx.x & 31, ty = threadIdx.x >> 5;
    const size_t xb = (size_t)b * 128 * 8192;
    #pragma unroll
    for (int j = 0; j < 4; ++j) {
        int c = ct*32 + ty + j*8;
        tile[ty + j*8][tx] = f2b(x[xb + (size_t)c * 8192 + (size_t)(nt*32 + tx)]);
    }
    __syncthreads();
    #pragma unroll
    for (int j = 0; j < 4; ++j) {
        int n = nt*32 + ty + j*8;
        xT[xb + (size_t)n * 128 + (size_t)(ct*32 + tx)] = tile[tx][ty + j*8];
    }
}

// ---------------------------------------------------------------------------
// Kernel 3: fused main. Grid 1024 x 512; 16 n per block; 7 barriers.
__global__ void __launch_bounds__(512)
k_main(const u16* __restrict__ xT, const float* __restrict__ coords,
       const int* __restrict__ idx, const float* __restrict__ Bg,
       const float* __restrict__ b1g, const float* __restrict__ b2g,
       const u16* __restrict__ Afrag, const u16* __restrict__ Wovfrag,
       const u16* __restrict__ W1frag, const u16* __restrict__ W2frag,
       const u16* __restrict__ W2Tfrag,
       const float* __restrict__ bAg, const float* __restrict__ sug,
       const float* __restrict__ bovg, const float* __restrict__ d0g,
       float* __restrict__ out)
{
    __shared__ __align__(16) u16   buf[256][136];    // x_nb rows (n,k) x c
    __shared__ __align__(16) u16   sH[256][40];      // H bf16 rows (n,k) x m
    __shared__ __align__(16) u16   s_qkb[16][136];   // qk bf16 [n][c]
    __shared__ __align__(16) u16   s_gb[16][40];     // g bf16 [n][m]
    __shared__ __align__(16) u16   s_wtb[16][136];   // W bf16 [n][c]
    __shared__ __align__(16) float s_xb[16][132];    // xbar+b2 f32 [n][c]
    __shared__ __align__(16) float s_del[256][4];
    __shared__ float s_sc[16][17];                   // raw scores
    __shared__ float s_attn[16][17];
    __shared__ u16   sHbar[32][18];                  // hbar bf16 [m][n]
    __shared__ float s_e0[16];
    __shared__ __align__(16) float s_b2[128], s_su[128];
    __shared__ float s_bA[128], s_bov[128], s_b1[32];
    __shared__ __align__(16) float sBgT[64][4];
    __shared__ int s_idx[256];

    const int tid = threadIdx.x;
    const int w = tid >> 6, l = tid & 63, lm = l & 15, lq = l >> 4;
    const int g0 = blockIdx.x * 16;
    const int bsel = g0 >> 13;
    const int n0 = g0 & 8191;
    const size_t bbase = ((size_t)bsel) << 13;
    const float inv_sqrtC = 0.08838834764831845f;

    // ---- preamble: biases/Bg + idx/delta gather + QK MFMA ----
    if (tid < 128) {
        s_bA[tid] = bAg[tid]; s_su[tid] = sug[tid];
        s_bov[tid] = bovg[tid]; s_b2[tid] = b2g[tid];
    } else if (tid < 160) {
        s_b1[tid-128] = b1g[tid-128];
    } else if (tid >= 256) {
        int q = tid - 256;
        sBgT[q >> 2][q & 3] = Bg[(q & 3)*64 + (q >> 2)];
    }
    const float c_d0 = *d0g;

    if (tid < 256) {
        int j = idx[(size_t)g0*16 + tid];
        s_idx[tid] = j;
        float4 cj = *(const float4*)&coords[(size_t)(bbase + j)*4];
        float4 cn = *(const float4*)&coords[(size_t)(g0 + (tid >> 4))*4];
        *(float4*)s_del[tid] = make_float4(cj.x-cn.x, cj.y-cn.y, cj.z-cn.z, cj.w-cn.w);
    }
    // QK = A*X: wave w = c-tile w. B from global xT rows g0+lm.
    f32x4 accq = {0.f, 0.f, 0.f, 0.f};
    {
        const bf16x8* Af = (const bf16x8*)Afrag;
        #pragma unroll
        for (int ks = 0; ks < 4; ++ks) {
            bf16x8 a = Af[(w*4 + ks)*64 + l];
            bf16x8 bfr = *(const bf16x8*)&xT[(((size_t)(g0 + lm)) << 7) + ks*32 + lq*8];
            accq = __builtin_amdgcn_mfma_f32_16x16x32_bf16(a, bfr, accq, 0, 0, 0);
        }
    }
    __syncthreads();   // B1

    // qk -> bf16 [n][c]
    {
        int c0 = w*16 + lq*4;
        *(u64*)&s_qkb[lm][c0] = pack4(accq[0] + s_bA[c0],   accq[1] + s_bA[c0+1],
                                      accq[2] + s_bA[c0+2], accq[3] + s_bA[c0+3]);
    }
    __syncthreads();   // B2

    // ---- big phase: H (all waves, E in registers) ; G (w0-1) ; e0t0 (w2-3) ;
    //      x_nb staging (all threads) ----
    {
        // x_nb staging: thread -> row tid>>1, 8 of 16 16B-chunks
        const int row = tid >> 1, ch0 = (tid & 1)*8;
        const size_t rbase = ((size_t)(bbase + s_idx[row])) << 7;
        #pragma unroll
        for (int cc = 0; cc < 8; ++cc) {
            int chunk = ch0 + cc;
            *(uint4*)&buf[row][chunk*8] = *(const uint4*)&xT[rbase + chunk*8];
        }
    }
    {
        // H = relu(E*W1 + b1): wave w owns m-tiles 2w, 2w+1
        const bf16x8* W1f = (const bf16x8*)W1frag;
        bf16x8 w1f[2][4];
        #pragma unroll
        for (int nt = 0; nt < 2; ++nt)
            #pragma unroll
            for (int ks = 0; ks < 4; ++ks) w1f[nt][ks] = W1f[(nt*4 + ks)*64 + l];
        // Bg columns this lane needs: f = ksp*32 + lq*8 + j
        float4 bgc[2][8];
        #pragma unroll
        for (int ksp = 0; ksp < 2; ++ksp)
            #pragma unroll
            for (int j = 0; j < 8; ++j)
                bgc[ksp][j] = *(const float4*)sBgT[ksp*32 + lq*8 + j];
        #pragma unroll
        for (int mi = 0; mi < 2; ++mi) {
            const int mt = w*2 + mi;
            float4 d = *(const float4*)s_del[mt*16 + lm];
            bf16x8 ea[4];
            #pragma unroll
            for (int ksp = 0; ksp < 2; ++ksp) {
                #pragma unroll
                for (int jp = 0; jp < 4; ++jp) {
                    float4 ga = bgc[ksp][jp*2], gb = bgc[ksp][jp*2+1];
                    float p0 = d.x*ga.x + d.y*ga.y + d.z*ga.z + d.w*ga.w;
                    float p1 = d.x*gb.x + d.y*gb.y + d.z*gb.z + d.w*gb.w;
                    p0 -= floorf(p0); p1 -= floorf(p1);
                    ((u32*)&ea[ksp])[jp]   = (u32)f2b(__builtin_amdgcn_sinf(p0))
                                           | ((u32)f2b(__builtin_amdgcn_sinf(p1)) << 16);
                    ((u32*)&ea[ksp+2])[jp] = (u32)f2b(__builtin_amdgcn_cosf(p0))
                                           | ((u32)f2b(__builtin_amdgcn_cosf(p1)) << 16);
                }
            }
            f32x4 acch[2] = {{0.f,0.f,0.f,0.f},{0.f,0.f,0.f,0.f}};
            #pragma unroll
            for (int ks = 0; ks < 4; ++ks) {
                acch[0] = __builtin_amdgcn_mfma_f32_16x16x32_bf16(ea[ks], w1f[0][ks], acch[0], 0,0,0);
                acch[1] = __builtin_amdgcn_mfma_f32_16x16x32_bf16(ea[ks], w1f[1][ks], acch[1], 0,0,0);
            }
            #pragma unroll
            for (int nt = 0; nt < 2; ++nt) {
                float b1v = s_b1[nt*16 + lm];
                #pragma unroll
                for (int r = 0; r < 4; ++r)
                    sH[mt*16 + lq*4 + r][nt*16 + lm] = f2b(fmaxf(acch[nt][r] + b1v, 0.f));
            }
        }
    }
    if (w < 2) {
        // G = W2*QK (2 m-tiles over waves 0-1)
        const bf16x8* W2f = (const bf16x8*)W2frag;
        f32x4 accg = {0.f,0.f,0.f,0.f};
        #pragma unroll
        for (int ks = 0; ks < 4; ++ks) {
            bf16x8 a = W2f[(w*4 + ks)*64 + l];
            bf16x8 bv = *(const bf16x8*)&s_qkb[lm][ks*32 + lq*8];
            accg = __builtin_amdgcn_mfma_f32_16x16x32_bf16(a, bv, accg, 0, 0, 0);
        }
        int m0 = w*16 + lq*4;
        *(u64*)&s_gb[lm][m0] = pack4(accg[0], accg[1], accg[2], accg[3]);
    } else if (w < 4) {
        // e0t0[n] = qk·b2 + x_n·su + d0 ; 8 threads per n
        int t = tid - 128, n = t >> 3, sub = t & 7, c0 = sub*16;
        uint4 q0 = *(const uint4*)&s_qkb[n][c0];
        uint4 q1 = *(const uint4*)&s_qkb[n][c0+8];
        uint4 x0 = *(const uint4*)&xT[(((size_t)(g0 + n)) << 7) + c0];
        uint4 x1 = *(const uint4*)&xT[(((size_t)(g0 + n)) << 7) + c0 + 8];
        float part = dot8(q0, &s_b2[c0]) + dot8(q1, &s_b2[c0+8])
                   + dot8(x0, &s_su[c0]) + dot8(x1, &s_su[c0+8]);
        part += __shfl_xor(part, 1);
        part += __shfl_xor(part, 2);
        part += __shfl_xor(part, 4);
        if (sub == 0) s_e0[n] = part + c_d0;
    }
    __syncthreads();   // B3

    // ---- scores: S = [Xnb | H] · [qk ; g], extract col n'=mt ----
    {
        bf16x8 bq4[5];
        #pragma unroll
        for (int ks = 0; ks < 4; ++ks) bq4[ks] = *(const bf16x8*)&s_qkb[lm][ks*32 + lq*8];
        bq4[4] = *(const bf16x8*)&s_gb[lm][lq*8];
        #pragma unroll
        for (int mi = 0; mi < 2; ++mi) {
            const int mt = w*2 + mi;
            f32x4 acc = {0.f,0.f,0.f,0.f};
            #pragma unroll
            for (int ks = 0; ks < 4; ++ks) {
                bf16x8 a = *(const bf16x8*)&buf[mt*16 + lm][ks*32 + lq*8];
                acc = __builtin_amdgcn_mfma_f32_16x16x32_bf16(a, bq4[ks], acc, 0, 0, 0);
            }
            {
                bf16x8 a = *(const bf16x8*)&sH[mt*16 + lm][lq*8];
                acc = __builtin_amdgcn_mfma_f32_16x16x32_bf16(a, bq4[4], acc, 0, 0, 0);
            }
            if (lm == mt) {
                #pragma unroll
                for (int r = 0; r < 4; ++r) s_sc[mt][lq*4 + r] = acc[r];
            }
        }
    }
    __syncthreads();   // B4

    // ---- softmax over K=16 ----
    if (tid < 256) {
        int n = tid >> 4, k = tid & 15;
        float s = (s_sc[n][k] + s_e0[n]) * inv_sqrtC;
        float mx = s;
        mx = fmaxf(mx, __shfl_xor(mx, 1, 16));
        mx = fmaxf(mx, __shfl_xor(mx, 2, 16));
        mx = fmaxf(mx, __shfl_xor(mx, 4, 16));
        mx = fmaxf(mx, __shfl_xor(mx, 8, 16));
        float ex = __expf(s - mx);
        float sm = ex;
        sm += __shfl_xor(sm, 1, 16);
        sm += __shfl_xor(sm, 2, 16);
        sm += __shfl_xor(sm, 4, 16);
        sm += __shfl_xor(sm, 8, 16);
        s_attn[n][k] = ex / sm;
    }
    __syncthreads();   // B5

    // ---- xbar (+b2) -> s_xb [n][c] ; hbar -> sHbar [m][n] ----
    {
        int n = tid >> 5, cs = tid & 31, c0 = cs*4;
        float a0[16];
        #pragma unroll
        for (int k = 0; k < 16; ++k) a0[k] = s_attn[n][k];
        float4 facc = *(const float4*)&s_b2[c0];
        #pragma unroll
        for (int k = 0; k < 16; ++k) {
            uint2 v = *(const uint2*)&buf[n*16 + k][c0];
            facc.x += a0[k]*bl(v.x); facc.y += a0[k]*bh(v.x);
            facc.z += a0[k]*bl(v.y); facc.w += a0[k]*bh(v.y);
        }
        *(float4*)&s_xb[n][c0] = facc;
        int m = tid & 31;
        float hacc = 0.f;
        #pragma unroll
        for (int k = 0; k < 16; ++k) hacc += a0[k] * b2f(sH[n*16 + k][m]);
        sHbar[m][n] = f2b(hacc);
    }
    __syncthreads();   // B6

    // ---- W = xbar + W2T*Hbar -> bf16 [n][c] ----
    {
        const bf16x8* W2Tf = (const bf16x8*)W2Tfrag;
        bf16x8 a = W2Tf[w*64 + l];
        bf16x8 bv;
        #pragma unroll
        for (int j = 0; j < 8; ++j) bv[j] = (short)sHbar[lq*8 + j][lm];
        f32x4 accw = {0.f,0.f,0.f,0.f};
        accw = __builtin_amdgcn_mfma_f32_16x16x32_bf16(a, bv, accw, 0, 0, 0);
        int c0 = w*16 + lq*4;
        float4 xb4 = *(const float4*)&s_xb[lm][c0];
        *(u64*)&s_wtb[lm][c0] = pack4(xb4.x + accw[0], xb4.y + accw[1],
                                      xb4.z + accw[2], xb4.w + accw[3]);
    }
    __syncthreads();   // B7

    // ---- OUT = Wov*W + bov -> global ----
    {
        const bf16x8* Wvf = (const bf16x8*)Wovfrag;
        f32x4 acco = {0.f,0.f,0.f,0.f};
        #pragma unroll
        for (int ks = 0; ks < 4; ++ks) {
            bf16x8 a = Wvf[(w*4 + ks)*64 + l];
            bf16x8 bv = *(const bf16x8*)&s_wtb[lm][ks*32 + lq*8];
            acco = __builtin_amdgcn_mfma_f32_16x16x32_bf16(a, bv, acco, 0, 0, 0);
        }
        #pragma unroll
        for (int r = 0; r < 4; ++r) {
            int o = w*16 + lq*4 + r;
            out[(((size_t)(bsel*128 + o)) << 13) + n0 + lm] = acco[r] + s_bov[o];
        }
    }
}

// ---------------------------------------------------------------------------
extern "C" void kernel_launch(void* const* d_in, const int* in_sizes, int n_in,
                              void* d_out, int out_size, void* d_ws, size_t ws_size,
                              hipStream_t stream)
{
    const float* x      = (const float*)d_in[0];
    const float* coords = (const float*)d_in[1];
    const int*   idx    = (const int*)d_in[2];
    const float* Bg     = (const float*)d_in[3];
    const float* W1     = (const float*)d_in[4];
    const float* b1     = (const float*)d_in[5];
    const float* W2     = (const float*)d_in[6];
    const float* b2     = (const float*)d_in[7];
    const float* Wq     = (const float*)d_in[8];
    const float* bq     = (const float*)d_in[9];
    const float* Wk     = (const float*)d_in[10];
    const float* bk     = (const float*)d_in[11];
    const float* Wv     = (const float*)d_in[12];
    const float* bv     = (const float*)d_in[13];
    const float* Wo     = (const float*)d_in[14];
    const float* bo     = (const float*)d_in[15];
    float* out = (float*)d_out;

    char* ws = (char*)d_ws;
    u16*   Afrag   = (u16*)(ws);              // 32768 B
    u16*   Wovfrag = (u16*)(ws + 32768);      // 32768 B
    u16*   W1frag  = (u16*)(ws + 65536);      // 8192 B
    u16*   W2frag  = (u16*)(ws + 73728);      // 8192 B
    u16*   W2Tfrag = (u16*)(ws + 81920);      // 8192 B
    float* bA      = (float*)(ws + 90112);    // 512 B
    float* su      = (float*)(ws + 90624);    // 512 B
    float* bov     = (float*)(ws + 91136);    // 512 B
    float* d0      = (float*)(ws + 91648);    // 16 B
    u16*   xT      = (u16*)(ws + 94208);      // 4 MiB

    k_prep<<<130, 512, 0, stream>>>(Wq, bq, Wk, bk, Wv, bv, Wo, bo, W1, W2,
                                    Afrag, Wovfrag, W1frag, W2frag, W2Tfrag,
                                    bA, su, bov, d0);
    k_tr<<<2048, 256, 0, stream>>>(x, xT);
    k_main<<<1024, 512, 0, stream>>>(xT, coords, idx, Bg, b1, b2,
                                     Afrag, Wovfrag, W1frag, W2frag, W2Tfrag,
                                     bA, su, bov, d0, out);
}